// Round 2
// baseline (357.579 us; speedup 1.0000x reference)
//
#include <hip/hip_runtime.h>
#include <stdint.h>

#define TT 2048
#define HH 16
#define LOG2E 1.44269504089f

typedef _Float16 f16;
typedef __attribute__((ext_vector_type(8))) _Float16 f16x8;
typedef __attribute__((ext_vector_type(4))) float f32x4;
typedef unsigned short ushort_t;

// async global->LDS, 16B per lane (GEMM only)
__device__ __forceinline__ void gl_lds16(const void* g, void* l){
  __builtin_amdgcn_global_load_lds(
      (__attribute__((address_space(1))) void*)(void*)g,
      (__attribute__((address_space(3))) void*)l, 16, 0, 0);
}

// barrier WITHOUT vmcnt drain: LDS ops done, but global loads stay in flight
__device__ __forceinline__ void lds_barrier(){
  __asm__ volatile("s_waitcnt lgkmcnt(0)\n\ts_barrier" ::: "memory");
}

// ---------------- block schedule (chunk = 8 k-tiles), LPT order ----------------
struct SchedT { unsigned short v[80]; };
static constexpr SchedT make_sched(){
  SchedT s{};
  int idx = 0;
  for (int size = 8; size >= 1; --size){
    for (int qt = 31; qt >= 8; --qt){
      int full = qt >> 3;
      int tail = (qt & 7) + 1;
      if (size == 8)
        for (int ci = 0; ci < full; ++ci)
          s.v[idx++] = (unsigned short)(qt | (ci << 8));
      if (tail == size)
        s.v[idx++] = (unsigned short)(qt | (full << 8));
    }
    s.v[idx++] = (unsigned short)(size - 1);
  }
  return s;
}
__constant__ SchedT SCHED = make_sched();

// prefix of partial-slot count: slots for qt' in [8, qt)
__device__ __forceinline__ int slot_base(int qt){
  return (qt < 16) ? 2 * (qt - 8)
       : (qt < 24) ? 16 + 3 * (qt - 16)
                   : 40 + 4 * (qt - 24);
}

// ---------------- convert x: f32 -> f16 ----------------
__global__ __launch_bounds__(256) void cvt_f2h_kernel(const float4* __restrict__ in,
                                                      uint2* __restrict__ out, int n4){
  int i = blockIdx.x * 256 + threadIdx.x;
  if (i >= n4) return;
  float4 v = in[i];
  union { f16 h[4]; uint2 u; } o;
  o.h[0] = (f16)v.x; o.h[1] = (f16)v.y; o.h[2] = (f16)v.z; o.h[3] = (f16)v.w;
  out[i] = o.u;
}

// ---------------- pack bias: lower-triangle 64x64 tiles of u32 = f16(gadj) | etype<<16 ----
// grid.x = 2*528 tiles; block 256 threads, 16 elems each.
__global__ __launch_bounds__(256) void pack_bias_kernel(const float* __restrict__ gadj,
                                                        const int* __restrict__ etype,
                                                        uint32_t* __restrict__ out){
  int bid = blockIdx.x;
  int b = bid / 528, ti = bid - b * 528;
  int qt = (int)((sqrtf(8.f * (float)ti + 1.f) - 1.f) * 0.5f);
  while ((qt + 1) * (qt + 2) / 2 <= ti) ++qt;
  while (qt * (qt + 1) / 2 > ti) --qt;
  int kt = ti - qt * (qt + 1) / 2;

  int t = threadIdx.x;
  int row = t >> 2, c0 = (t & 3) << 4;
  size_t src = ((size_t)b * TT + qt * 64 + row) * TT + kt * 64 + c0;
  uint32_t* dst = out + (size_t)bid * 4096 + row * 64 + c0;
  #pragma unroll
  for (int v4 = 0; v4 < 4; ++v4){
    float4 g = *(const float4*)(gadj + src + v4 * 4);
    int4   e = *(const int4*)(etype + src + v4 * 4);
    union { f16 h; ushort_t u; } c;
    uint4 o;
    c.h = (f16)g.x; o.x = (uint32_t)c.u | ((uint32_t)e.x << 16);
    c.h = (f16)g.y; o.y = (uint32_t)c.u | ((uint32_t)e.y << 16);
    c.h = (f16)g.z; o.z = (uint32_t)c.u | ((uint32_t)e.z << 16);
    c.h = (f16)g.w; o.w = (uint32_t)c.u | ((uint32_t)e.w << 16);
    *(uint4*)(dst + v4 * 4) = o;
  }
}

// ---------------- transpose+convert: f32 [R][C] -> f16 [C][R] ----------------
__global__ __launch_bounds__(256) void transpose_cvt_kernel(const float* __restrict__ in,
                                                            f16* __restrict__ out, int R, int C){
  __shared__ float tile[64][65];
  int c0 = blockIdx.x * 64, r0 = blockIdx.y * 64;
  int t = threadIdx.x;
  int row = t >> 2, cs = (t & 3) << 4;
  const float4* src = (const float4*)(in + (size_t)(r0 + row) * C + c0 + cs);
  float4 a = src[0], b = src[1], c = src[2], d = src[3];
  float* tr = &tile[row][cs];
  tr[0]=a.x; tr[1]=a.y; tr[2]=a.z;  tr[3]=a.w;
  tr[4]=b.x; tr[5]=b.y; tr[6]=b.z;  tr[7]=b.w;
  tr[8]=c.x; tr[9]=c.y; tr[10]=c.z; tr[11]=c.w;
  tr[12]=d.x;tr[13]=d.y;tr[14]=d.z; tr[15]=d.w;
  __syncthreads();
  f16 tmp[16];
  #pragma unroll
  for (int j = 0; j < 16; ++j) tmp[j] = (f16)tile[cs + j][row];
  f16* dst = out + (size_t)(c0 + row) * R + r0 + cs;
  *(uint4*)dst = *(uint4*)&tmp[0];
  *(uint4*)(dst + 8) = *(uint4*)&tmp[8];
}

// ---------------- GEMM: C[M][N] = A[M][K] @ Bt[N][K]^T ----------------
__global__ __launch_bounds__(256) void gemm_f16_kernel(const f16* __restrict__ A,
                                                       const f16* __restrict__ Bt,
                                                       void* __restrict__ Cout,
                                                       int M, int N, int K, int out_f32){
  __shared__ __align__(16) f16 As[128 * 32];
  __shared__ __align__(16) f16 Bs[128 * 32];
  int t = threadIdx.x;
  int w = t >> 6, lane = t & 63;
  int wm = (w >> 1) * 64, wn = (w & 1) * 64;
  int lrow = lane & 15, quad = lane >> 4;
  int bm = blockIdx.y, bn = blockIdx.x;

  f32x4 acc[4][4];
  for (int i = 0; i < 4; ++i)
    for (int j = 0; j < 4; ++j)
      for (int r = 0; r < 4; ++r) acc[i][j][r] = 0.f;

  const int nk = K >> 5;
  for (int kt = 0; kt < nk; ++kt){
    int k0 = kt << 5;
    __syncthreads();
    #pragma unroll
    for (int i = 0; i < 2; ++i){
      int c = (w << 7) + (i << 6) + lane;
      gl_lds16(A  + (size_t)((bm << 7) + (c >> 2)) * K + k0 + ((c & 3) << 3),
               As + ((w << 7) + (i << 6)) * 8);
      gl_lds16(Bt + (size_t)((bn << 7) + (c >> 2)) * K + k0 + ((c & 3) << 3),
               Bs + ((w << 7) + (i << 6)) * 8);
    }
    __syncthreads();
    f16x8 af[4], bfr[4];
    #pragma unroll
    for (int mi = 0; mi < 4; ++mi)
      af[mi] = *(const f16x8*)(As + (wm + mi * 16 + lrow) * 32 + quad * 8);
    #pragma unroll
    for (int ni = 0; ni < 4; ++ni)
      bfr[ni] = *(const f16x8*)(Bs + (wn + ni * 16 + lrow) * 32 + quad * 8);
    #pragma unroll
    for (int mi = 0; mi < 4; ++mi)
      #pragma unroll
      for (int ni = 0; ni < 4; ++ni)
        acc[mi][ni] = __builtin_amdgcn_mfma_f32_16x16x32_f16(af[mi], bfr[ni], acc[mi][ni], 0, 0, 0);
  }

  #pragma unroll
  for (int mi = 0; mi < 4; ++mi)
    #pragma unroll
    for (int ni = 0; ni < 4; ++ni)
      #pragma unroll
      for (int r = 0; r < 4; ++r){
        int row = (bm << 7) + wm + mi * 16 + quad * 4 + r;
        int col = (bn << 7) + wn + ni * 16 + lrow;
        float val = acc[mi][ni][r];
        if (out_f32) ((float*)Cout)[(size_t)row * N + col] = val;
        else         ((f16*)Cout)[(size_t)row * N + col] = (f16)val;
      }
}

// ---------------- fused causal graph attention, split-K chunks of 8 tiles ----------------
// Software-pipelined: K/V (4x uint4) + packed bias (16x u32) prefetched one tile ahead.
__global__ __launch_bounds__(256, 4) void attn_kernel(const f16* __restrict__ qkv,
                                                      const uint32_t* __restrict__ pbias,
                                                      const float* __restrict__ adj_bias,
                                                      const float* __restrict__ edge_table,
                                                      f16* __restrict__ attn_out,
                                                      f16* __restrict__ Opart,
                                                      float* __restrict__ MLpart){
  __shared__ __align__(16) f16 Ks[64 * 72];
  __shared__ __align__(16) f16 Vt[64 * 72];   // transposed [hd][key], xor-swizzled 16B blocks
  __shared__ __align__(16) f16 Ps[4][16 * 72];
  __shared__ float edge_lds[8 * 33];          // 8 replicas, stride 33 (bank spread)

  int bx = blockIdx.x;
  int bh = bx & 31;
  int h = bh & 15, b = bh >> 4;
  int ej = SCHED.v[bx >> 5];
  int qt = ej & 31, ci = ej >> 8;
  int ksrt = ci << 3;
  int kend = min(qt, ksrt + 7);
  bool whole = (qt < 8);

  int t = threadIdx.x;
  int w = t >> 6, lane = t & 63;
  int lrow = lane & 15, quad = lane >> 4;

  if (t < 136){
    int cp = t / 17, e = t - cp * 17;
    edge_lds[cp * 33 + e] = edge_table[e * HH + h] * LOG2E;
  }
  float adjb = adj_bias[h] * LOG2E;
  int erep = (lane & 7) * 33;

  int q0 = qt * 64 + w * 16;
  const size_t qrow = ((size_t)b * TT + q0 + lrow) * 3072 + h * 64;
  f16x8 qf0 = *(const f16x8*)(qkv + qrow + quad * 8);
  f16x8 qf1 = *(const f16x8*)(qkv + qrow + 32 + quad * 8);

  f32x4 o[4];
  for (int i = 0; i < 4; ++i)
    for (int r = 0; r < 4; ++r) o[i][r] = 0.f;
  float mrun[4] = {-1e30f, -1e30f, -1e30f, -1e30f};
  float lrun[4] = {0.f, 0.f, 0.f, 0.f};

  // staging geometry (per thread, both halves): key = c>>3, hd0 = (c&7)*8
  const int keyA = t >> 3,        hdA = (t & 7) << 3;
  const int keyB = 32 + (t >> 3), hdB = hdA;
  const int sA = ((keyA >> 3) ^ (hdA >> 3)) & 7;
  const int sB = ((keyB >> 3) ^ (hdB >> 3)) & 7;
  const f16* kbase = qkv + (size_t)b * TT * 3072 + 1024 + h * 64;
  const f16* vbase = qkv + (size_t)b * TT * 3072 + 2048 + h * 64;

  const float SCL = 0.125f * LOG2E;   // score scale, log2-domain

  // bias tile addressing (triangle-compressed layout)
  const int tribase = b * 528 + ((qt * (qt + 1)) >> 1);
  const size_t rowbase = (size_t)((w * 16 + quad * 4) * 64 + lrow);
  const int qgb = q0 + quad * 4;

  // prefetch register sets
  uint4 ka, kb, va, vb;
  uint32_t bA[16], bB[16];

  auto issue_kv = [&](int kt){
    const f16* kr = kbase + (size_t)(kt * 64) * 3072;
    const f16* vr = vbase + (size_t)(kt * 64) * 3072;
    ka = *(const uint4*)(kr + (size_t)keyA * 3072 + hdA);
    kb = *(const uint4*)(kr + (size_t)keyB * 3072 + hdB);
    va = *(const uint4*)(vr + (size_t)keyA * 3072 + hdA);
    vb = *(const uint4*)(vr + (size_t)keyB * 3072 + hdB);
  };
  auto issue_bias = [&](int kt, uint32_t (&bd)[16]){
    const uint32_t* tp = pbias + (size_t)(tribase + kt) * 4096 + rowbase;
    #pragma unroll
    for (int nb = 0; nb < 4; ++nb)
      #pragma unroll
      for (int r = 0; r < 4; ++r)
        bd[nb * 4 + r] = tp[(size_t)r * 64 + nb * 16];
  };

  auto process = [&](int kt2, uint32_t (&bc)[16], uint32_t (&bn)[16]){
    __asm__ volatile("s_waitcnt vmcnt(0)" ::: "memory");  // cur tile regs arrived
    lds_barrier();                                        // prev tile LDS reads done
    // ---- LDS writes from regs: K rows (b128), V transposed (scalar, swizzled)
    *(uint4*)(Ks + keyA * 72 + hdA) = ka;
    *(uint4*)(Ks + keyB * 72 + hdB) = kb;
    {
      union { uint4 u; f16 hh[8]; } ua, ub;
      ua.u = va; ub.u = vb;
      #pragma unroll
      for (int jj = 0; jj < 8; ++jj){
        Vt[(hdA + jj) * 72 + (sA << 3) + (keyA & 7)] = ua.hh[jj];
        Vt[(hdB + jj) * 72 + (sB << 3) + (keyB & 7)] = ub.hh[jj];
      }
    }
    // ---- issue next tile's loads (fly across barrier + compute)
    if (kt2 < kend){ issue_kv(kt2 + 1); issue_bias(kt2 + 1, bn); }
    lds_barrier();

    // ---- S = Q K^T
    f32x4 sf[4];
    #pragma unroll
    for (int nb = 0; nb < 4; ++nb){
      f32x4 s = {0.f, 0.f, 0.f, 0.f};
      f16x8 kf0 = *(const f16x8*)(Ks + (nb * 16 + lrow) * 72 + quad * 8);
      f16x8 kf1 = *(const f16x8*)(Ks + (nb * 16 + lrow) * 72 + 32 + quad * 8);
      s = __builtin_amdgcn_mfma_f32_16x16x32_f16(qf0, kf0, s, 0, 0, 0);
      s = __builtin_amdgcn_mfma_f32_16x16x32_f16(qf1, kf1, s, 0, 0, 0);
      sf[nb] = s;
    }

    // ---- bias + causal mask (C-layout: row = quad*4+r, col = lrow), log2-domain
    int kgb = kt2 * 64 + lrow;
    float sarr[4][4];
    bool diag = (kt2 == qt);
    #pragma unroll
    for (int nb = 0; nb < 4; ++nb){
      int kg = kgb + nb * 16;
      #pragma unroll
      for (int r = 0; r < 4; ++r){
        float v;
        if (diag && kg > qgb + r) v = -1e30f;
        else {
          uint32_t bp = bc[nb * 4 + r];
          union { ushort_t u; f16 h; } cv; cv.u = (ushort_t)bp;
          v = sf[nb][r] * SCL + adjb * (float)cv.h + edge_lds[erep + (bp >> 16)];
        }
        sarr[nb][r] = v;
      }
    }

    // ---- online softmax, deferred-max (skip rescale unless max grew > 5 log2 units)
    float mx[4];
    bool need = false;
    #pragma unroll
    for (int r = 0; r < 4; ++r){
      float m_ = fmaxf(fmaxf(sarr[0][r], sarr[1][r]), fmaxf(sarr[2][r], sarr[3][r]));
      m_ = fmaxf(m_, __shfl_xor(m_, 1));
      m_ = fmaxf(m_, __shfl_xor(m_, 2));
      m_ = fmaxf(m_, __shfl_xor(m_, 4));
      m_ = fmaxf(m_, __shfl_xor(m_, 8));
      mx[r] = m_;
      need = need || (m_ > mrun[r] + 5.0f);
    }
    if (__any(need)){
      #pragma unroll
      for (int r = 0; r < 4; ++r){
        float mnew = fmaxf(mrun[r], mx[r]);
        float alpha = exp2f(mrun[r] - mnew);
        lrun[r] *= alpha;
        #pragma unroll
        for (int nbh = 0; nbh < 4; ++nbh) o[nbh][r] *= alpha;
        mrun[r] = mnew;
      }
    }
    float pv_[4][4];
    #pragma unroll
    for (int r = 0; r < 4; ++r){
      float rs = 0.f;
      #pragma unroll
      for (int nb = 0; nb < 4; ++nb){
        float p = exp2f(sarr[nb][r] - mrun[r]);
        pv_[nb][r] = p; rs += p;
      }
      rs += __shfl_xor(rs, 1); rs += __shfl_xor(rs, 2);
      rs += __shfl_xor(rs, 4); rs += __shfl_xor(rs, 8);
      lrun[r] += rs;
    }

    // ---- P: C-layout -> LDS (pitch 72) -> A-layout (wave-private)
    f16* Pw = &Ps[w][0];
    #pragma unroll
    for (int nb = 0; nb < 4; ++nb)
      #pragma unroll
      for (int r = 0; r < 4; ++r)
        Pw[(quad * 4 + r) * 72 + nb * 16 + lrow] = (f16)pv_[nb][r];
    __asm__ volatile("s_waitcnt lgkmcnt(0)" ::: "memory");

    // ---- O += P V  (Vt b128 fragments, swizzled)
    #pragma unroll
    for (int cc = 0; cc < 2; ++cc){
      f16x8 pf = *(const f16x8*)(Pw + lrow * 72 + cc * 32 + quad * 8);
      #pragma unroll
      for (int nbh = 0; nbh < 4; ++nbh){
        int hd = nbh * 16 + lrow;
        int sb = (hd >> 3) & 7;
        f16x8 vf = *(const f16x8*)(Vt + hd * 72 + (((cc * 4 + quad) ^ sb) << 3));
        o[nbh] = __builtin_amdgcn_mfma_f32_16x16x32_f16(pf, vf, o[nbh], 0, 0, 0);
      }
    }
  };

  // ---- pipelined driver: 2x unrolled ping-pong, no reg copy
  issue_kv(ksrt); issue_bias(ksrt, bA);
  for (int kt2 = ksrt; ; ){
    process(kt2, bA, bB);
    if (++kt2 > kend) break;
    process(kt2, bB, bA);
    if (++kt2 > kend) break;
  }

  if (whole){
    float inv[4];
    #pragma unroll
    for (int r = 0; r < 4; ++r) inv[r] = 1.0f / lrun[r];
    #pragma unroll
    for (int nbh = 0; nbh < 4; ++nbh)
      #pragma unroll
      for (int r = 0; r < 4; ++r){
        int qg = q0 + quad * 4 + r;
        int col = h * 64 + nbh * 16 + lrow;
        attn_out[((size_t)b * TT + qg) * 1024 + col] = (f16)(o[nbh][r] * inv[r]);
      }
  } else {
    int slot = bh * 72 + slot_base(qt) + ci;
    f16* Ob = Opart + (size_t)slot * 4096;
    #pragma unroll
    for (int nbh = 0; nbh < 4; ++nbh)
      #pragma unroll
      for (int r = 0; r < 4; ++r)
        Ob[(w * 16 + quad * 4 + r) * 64 + nbh * 16 + lrow] = (f16)o[nbh][r];
    if (lrow == 0){
      #pragma unroll
      for (int r = 0; r < 4; ++r){
        int qq = w * 16 + quad * 4 + r;
        MLpart[(size_t)slot * 128 + qq] = mrun[r];
        MLpart[(size_t)slot * 128 + 64 + qq] = lrun[r];
      }
    }
  }
}

// ---------------- combine 2..4 partial chunks for qt>=8 ----------------
__global__ __launch_bounds__(256) void combine_kernel(const f16* __restrict__ Opart,
                                                      const float* __restrict__ ML,
                                                      f16* __restrict__ attn_out){
  int qt = blockIdx.x + 8;          // 8..31
  int bh = blockIdx.y;              // 0..31
  int nch = (qt >> 3) + 1;          // 2..4
  int slot0 = bh * 72 + slot_base(qt);
  int t = threadIdx.x;
  int q = t >> 2;
  int hd0 = (t & 3) << 4;

  float m[4], l[4];
  float M = -1e30f;
  #pragma unroll
  for (int c = 0; c < 4; ++c){
    if (c < nch){
      m[c] = ML[(size_t)(slot0 + c) * 128 + q];
      l[c] = ML[(size_t)(slot0 + c) * 128 + 64 + q];
      M = fmaxf(M, m[c]);
    } else { m[c] = -1e30f; l[c] = 0.f; }
  }
  float acc[16];
  #pragma unroll
  for (int i = 0; i < 16; ++i) acc[i] = 0.f;
  float L = 0.f;
  #pragma unroll
  for (int c = 0; c < 4; ++c){
    if (c < nch){
      float wgt = exp2f(m[c] - M);
      L += l[c] * wgt;
      const f16* O = Opart + (size_t)(slot0 + c) * 4096 + q * 64 + hd0;
      f16x8 a0 = *(const f16x8*)O, a1 = *(const f16x8*)(O + 8);
      #pragma unroll
      for (int i = 0; i < 8; ++i){
        acc[i]     += (float)a0[i] * wgt;
        acc[i + 8] += (float)a1[i] * wgt;
      }
    }
  }
  float invL = 1.0f / L;
  f16 outv[16];
  #pragma unroll
  for (int i = 0; i < 16; ++i) outv[i] = (f16)(acc[i] * invL);
  int b = bh >> 4, h = bh & 15;
  f16* dst = attn_out + ((size_t)b * TT + qt * 64 + q) * 1024 + h * 64 + hd0;
  *(uint4*)dst = *(uint4*)&outv[0];
  *(uint4*)(dst + 8) = *(uint4*)&outv[8];
}

extern "C" void kernel_launch(void* const* d_in, const int* in_sizes, int n_in,
                              void* d_out, int out_size, void* d_ws, size_t ws_size,
                              hipStream_t stream){
  (void)in_sizes; (void)n_in; (void)out_size; (void)ws_size;
  const float* x_f32  = (const float*)d_in[0];
  const float* gadj   = (const float*)d_in[1];
  const int*   etype  = (const int*)d_in[2];
  const float* wqkv   = (const float*)d_in[3];
  const float* wproj  = (const float*)d_in[4];
  const float* adjb   = (const float*)d_in[5];
  const float* etab   = (const float*)d_in[6];

  // workspace layout (peak ~72 MB):
  //  [0,8)    x_f16, reused as attn_out
  //  [8,32)   qkv
  //  [32,38)  wqkvT (dead after qkv GEMM) -- aliased by Opart [32,50.9)
  //  [51,53)  wprojT
  //  [53,54.2) MLpart
  //  [55,71.9) pbias (triangle-compressed u32 tiles)
  char* ws = (char*)d_ws;
  f16*     x_f16  = (f16*)(ws);
  f16*     qkv    = (f16*)(ws + (8u  << 20));
  f16*     wqkvT  = (f16*)(ws + (32u << 20));
  f16*     Opart  = (f16*)(ws + (32u << 20));
  f16*     wprojT = (f16*)(ws + (51u << 20));
  float*   MLpart = (float*)(ws + (53u << 20));
  uint32_t* pbias = (uint32_t*)(ws + (55u << 20));
  f16*     attn_o = x_f16;  // reuse

  cvt_f2h_kernel<<<4096, 256, 0, stream>>>((const float4*)x_f32, (uint2*)x_f16, 1048576);
  pack_bias_kernel<<<1056, 256, 0, stream>>>(gadj, etype, pbias);
  transpose_cvt_kernel<<<dim3(48, 16), 256, 0, stream>>>(wqkv, wqkvT, 1024, 3072);
  transpose_cvt_kernel<<<dim3(16, 16), 256, 0, stream>>>(wproj, wprojT, 1024, 1024);
  gemm_f16_kernel<<<dim3(24, 32), 256, 0, stream>>>(x_f16, wqkvT, qkv, 4096, 3072, 1024, 0);
  attn_kernel<<<2560, 256, 0, stream>>>(qkv, pbias, adjb, etab, attn_o, Opart, MLpart);
  combine_kernel<<<dim3(24, 32), 256, 0, stream>>>(Opart, MLpart, attn_o);
  gemm_f16_kernel<<<dim3(8, 32), 256, 0, stream>>>(attn_o, wprojT, d_out, 4096, 1024, 1024, 1);
}

// Round 3
// 295.703 us; speedup vs baseline: 1.2093x; 1.2093x over previous
//
#include <hip/hip_runtime.h>
#include <stdint.h>

#define TT 2048
#define HH 16
#define LOG2E 1.44269504089f

typedef _Float16 f16;
typedef __attribute__((ext_vector_type(8))) _Float16 f16x8;
typedef __attribute__((ext_vector_type(4))) float f32x4;
typedef unsigned short ushort_t;

// async global->LDS, 16B per lane (GEMM only)
__device__ __forceinline__ void gl_lds16(const void* g, void* l){
  __builtin_amdgcn_global_load_lds(
      (__attribute__((address_space(1))) void*)(void*)g,
      (__attribute__((address_space(3))) void*)l, 16, 0, 0);
}

// barrier WITHOUT vmcnt drain: LDS ops done, but global loads stay in flight
__device__ __forceinline__ void lds_barrier(){
  __asm__ volatile("s_waitcnt lgkmcnt(0)\n\ts_barrier" ::: "memory");
}

// ---------------- block schedule (chunk = 8 k-tiles), LPT order ----------------
struct SchedT { unsigned short v[80]; };
static constexpr SchedT make_sched(){
  SchedT s{};
  int idx = 0;
  for (int size = 8; size >= 1; --size){
    for (int qt = 31; qt >= 8; --qt){
      int full = qt >> 3;
      int tail = (qt & 7) + 1;
      if (size == 8)
        for (int ci = 0; ci < full; ++ci)
          s.v[idx++] = (unsigned short)(qt | (ci << 8));
      if (tail == size)
        s.v[idx++] = (unsigned short)(qt | (full << 8));
    }
    s.v[idx++] = (unsigned short)(size - 1);
  }
  return s;
}
__constant__ SchedT SCHED = make_sched();

// prefix of partial-slot count: slots for qt' in [8, qt)
__device__ __forceinline__ int slot_base(int qt){
  return (qt < 16) ? 2 * (qt - 8)
       : (qt < 24) ? 16 + 3 * (qt - 16)
                   : 40 + 4 * (qt - 24);
}

// ---------------- convert x: f32 -> f16 ----------------
__global__ __launch_bounds__(256) void cvt_f2h_kernel(const float4* __restrict__ in,
                                                      uint2* __restrict__ out, int n4){
  int i = blockIdx.x * 256 + threadIdx.x;
  if (i >= n4) return;
  float4 v = in[i];
  union { f16 h[4]; uint2 u; } o;
  o.h[0] = (f16)v.x; o.h[1] = (f16)v.y; o.h[2] = (f16)v.z; o.h[3] = (f16)v.w;
  out[i] = o.u;
}

// ---------------- pack bias: lower-triangle 64x64 tiles, FRAGMENT order ----------------
// out[tile][t][j]: t = attn thread id (w*64 + quad*16 + lrow), j = nb*4 + r.
// element (qrow = (t>>6)*16 + ((t>>4)&3)*4 + r, col = nb*16 + (t&15)) of the tile.
// value = f16(gadj) | etype<<16. Coalesced reads, scattered u32 writes (one-shot).
__global__ __launch_bounds__(256) void pack_bias_kernel(const float* __restrict__ gadj,
                                                        const int* __restrict__ etype,
                                                        uint32_t* __restrict__ out){
  int bid = blockIdx.x;
  int b = bid / 528, ti = bid - b * 528;
  int qt = (int)((sqrtf(8.f * (float)ti + 1.f) - 1.f) * 0.5f);
  while ((qt + 1) * (qt + 2) / 2 <= ti) ++qt;
  while (qt * (qt + 1) / 2 > ti) --qt;
  int kt = ti - qt * (qt + 1) / 2;

  int t = threadIdx.x;
  int row = t >> 2, c0 = (t & 3) << 4;     // this thread reads row, cols c0..c0+15
  size_t src = ((size_t)b * TT + qt * 64 + row) * TT + kt * 64 + c0;
  uint32_t* dst = out + (size_t)bid * 4096;
  // fragment coords of (row, col): w=row>>4, quad=(row&15)>>2, r=row&3, nb=col>>4=t&3, lrow=col&15
  int wq = (row >> 4) * 64 + ((row & 15) >> 2) * 16;   // + lrow gives t'
  int jbase = (t & 3) * 4 + (row & 3);                 // nb*4 + r
  #pragma unroll
  for (int v4 = 0; v4 < 4; ++v4){
    float4 g = *(const float4*)(gadj + src + v4 * 4);
    int4   e = *(const int4*)(etype + src + v4 * 4);
    union { f16 h; ushort_t u; } c;
    c.h = (f16)g.x; dst[(wq + v4 * 4 + 0) * 16 + jbase] = (uint32_t)c.u | ((uint32_t)e.x << 16);
    c.h = (f16)g.y; dst[(wq + v4 * 4 + 1) * 16 + jbase] = (uint32_t)c.u | ((uint32_t)e.y << 16);
    c.h = (f16)g.z; dst[(wq + v4 * 4 + 2) * 16 + jbase] = (uint32_t)c.u | ((uint32_t)e.z << 16);
    c.h = (f16)g.w; dst[(wq + v4 * 4 + 3) * 16 + jbase] = (uint32_t)c.u | ((uint32_t)e.w << 16);
  }
}

// ---------------- transpose+convert: f32 [R][C] -> f16 [C][R] ----------------
__global__ __launch_bounds__(256) void transpose_cvt_kernel(const float* __restrict__ in,
                                                            f16* __restrict__ out, int R, int C){
  __shared__ float tile[64][65];
  int c0 = blockIdx.x * 64, r0 = blockIdx.y * 64;
  int t = threadIdx.x;
  int row = t >> 2, cs = (t & 3) << 4;
  const float4* src = (const float4*)(in + (size_t)(r0 + row) * C + c0 + cs);
  float4 a = src[0], b = src[1], c = src[2], d = src[3];
  float* tr = &tile[row][cs];
  tr[0]=a.x; tr[1]=a.y; tr[2]=a.z;  tr[3]=a.w;
  tr[4]=b.x; tr[5]=b.y; tr[6]=b.z;  tr[7]=b.w;
  tr[8]=c.x; tr[9]=c.y; tr[10]=c.z; tr[11]=c.w;
  tr[12]=d.x;tr[13]=d.y;tr[14]=d.z; tr[15]=d.w;
  __syncthreads();
  f16 tmp[16];
  #pragma unroll
  for (int j = 0; j < 16; ++j) tmp[j] = (f16)tile[cs + j][row];
  f16* dst = out + (size_t)(c0 + row) * R + r0 + cs;
  *(uint4*)dst = *(uint4*)&tmp[0];
  *(uint4*)(dst + 8) = *(uint4*)&tmp[8];
}

// ---------------- GEMM: C[M][N] = A[M][K] @ Bt[N][K]^T ----------------
__global__ __launch_bounds__(256) void gemm_f16_kernel(const f16* __restrict__ A,
                                                       const f16* __restrict__ Bt,
                                                       void* __restrict__ Cout,
                                                       int M, int N, int K, int out_f32){
  __shared__ __align__(16) f16 As[128 * 32];
  __shared__ __align__(16) f16 Bs[128 * 32];
  int t = threadIdx.x;
  int w = t >> 6, lane = t & 63;
  int wm = (w >> 1) * 64, wn = (w & 1) * 64;
  int lrow = lane & 15, quad = lane >> 4;
  int bm = blockIdx.y, bn = blockIdx.x;

  f32x4 acc[4][4];
  for (int i = 0; i < 4; ++i)
    for (int j = 0; j < 4; ++j)
      for (int r = 0; r < 4; ++r) acc[i][j][r] = 0.f;

  const int nk = K >> 5;
  for (int kt = 0; kt < nk; ++kt){
    int k0 = kt << 5;
    __syncthreads();
    #pragma unroll
    for (int i = 0; i < 2; ++i){
      int c = (w << 7) + (i << 6) + lane;
      gl_lds16(A  + (size_t)((bm << 7) + (c >> 2)) * K + k0 + ((c & 3) << 3),
               As + ((w << 7) + (i << 6)) * 8);
      gl_lds16(Bt + (size_t)((bn << 7) + (c >> 2)) * K + k0 + ((c & 3) << 3),
               Bs + ((w << 7) + (i << 6)) * 8);
    }
    __syncthreads();
    f16x8 af[4], bfr[4];
    #pragma unroll
    for (int mi = 0; mi < 4; ++mi)
      af[mi] = *(const f16x8*)(As + (wm + mi * 16 + lrow) * 32 + quad * 8);
    #pragma unroll
    for (int ni = 0; ni < 4; ++ni)
      bfr[ni] = *(const f16x8*)(Bs + (wn + ni * 16 + lrow) * 32 + quad * 8);
    #pragma unroll
    for (int mi = 0; mi < 4; ++mi)
      #pragma unroll
      for (int ni = 0; ni < 4; ++ni)
        acc[mi][ni] = __builtin_amdgcn_mfma_f32_16x16x32_f16(af[mi], bfr[ni], acc[mi][ni], 0, 0, 0);
  }

  #pragma unroll
  for (int mi = 0; mi < 4; ++mi)
    #pragma unroll
    for (int ni = 0; ni < 4; ++ni)
      #pragma unroll
      for (int r = 0; r < 4; ++r){
        int row = (bm << 7) + wm + mi * 16 + quad * 4 + r;
        int col = (bn << 7) + wn + ni * 16 + lrow;
        float val = acc[mi][ni][r];
        if (out_f32) ((float*)Cout)[(size_t)row * N + col] = val;
        else         ((f16*)Cout)[(size_t)row * N + col] = (f16)val;
      }
}

// ---------------- fused causal graph attention, split-K chunks of 8 tiles ----------------
// Pipelined: K/V prefetched 1 tile ahead in named uint4 regs; bias (fragment-order, 4x dwordx4)
// issued before the compute barrier and consumed at the mask step. No arrays escape; no manual vmcnt.
__global__ __launch_bounds__(256, 4) void attn_kernel(const f16* __restrict__ qkv,
                                                      const uint32_t* __restrict__ pbias,
                                                      const float* __restrict__ adj_bias,
                                                      const float* __restrict__ edge_table,
                                                      f16* __restrict__ attn_out,
                                                      f16* __restrict__ Opart,
                                                      float* __restrict__ MLpart){
  __shared__ __align__(16) f16 Ks[64 * 72];
  __shared__ __align__(16) f16 Vt[64 * 72];   // transposed [hd][key], xor-swizzled 16B blocks
  __shared__ __align__(16) f16 Ps[4][16 * 72];
  __shared__ float edge_lds[8 * 33];          // 8 replicas, stride 33 (bank spread)

  int bx = blockIdx.x;
  int bh = bx & 31;
  int h = bh & 15, b = bh >> 4;
  int ej = SCHED.v[bx >> 5];
  int qt = ej & 31, ci = ej >> 8;
  int ksrt = ci << 3;
  int kend = min(qt, ksrt + 7);
  bool whole = (qt < 8);

  int t = threadIdx.x;
  int w = t >> 6, lane = t & 63;
  int lrow = lane & 15, quad = lane >> 4;

  if (t < 136){
    int cp = t / 17, e = t - cp * 17;
    edge_lds[cp * 33 + e] = edge_table[e * HH + h] * LOG2E;
  }
  float adjb = adj_bias[h] * LOG2E;
  int erep = (lane & 7) * 33;

  int q0 = qt * 64 + w * 16;
  const size_t qrow = ((size_t)b * TT + q0 + lrow) * 3072 + h * 64;
  f16x8 qf0 = *(const f16x8*)(qkv + qrow + quad * 8);
  f16x8 qf1 = *(const f16x8*)(qkv + qrow + 32 + quad * 8);

  f32x4 o[4];
  for (int i = 0; i < 4; ++i)
    for (int r = 0; r < 4; ++r) o[i][r] = 0.f;
  float mrun[4] = {-1e30f, -1e30f, -1e30f, -1e30f};
  float lrun[4] = {0.f, 0.f, 0.f, 0.f};

  // staging geometry (per thread, both halves): key = c>>3, hd0 = (c&7)*8
  const int keyA = t >> 3,        hdA = (t & 7) << 3;
  const int keyB = 32 + (t >> 3), hdB = hdA;
  const int sA = ((keyA >> 3) ^ (hdA >> 3)) & 7;
  const int sB = ((keyB >> 3) ^ (hdB >> 3)) & 7;
  const f16* kbase = qkv + (size_t)b * TT * 3072 + 1024 + h * 64;
  const f16* vbase = qkv + (size_t)b * TT * 3072 + 2048 + h * 64;
  const size_t koffA = (size_t)keyA * 3072 + hdA;
  const size_t koffB = (size_t)keyB * 3072 + hdB;

  const float SCL = 0.125f * LOG2E;   // score scale, log2-domain

  // bias tile addressing (triangle-compressed, fragment-order layout)
  const int tribase = b * 528 + ((qt * (qt + 1)) >> 1);
  const uint32_t* bthread = pbias + ((size_t)t << 4);
  const int qgb = q0 + quad * 4;

  // ---- prefetch first tile's K/V into named regs
  uint4 ka, kb, va, vb;
  {
    const f16* kr = kbase + (size_t)(ksrt * 64) * 3072;
    const f16* vr = vbase + (size_t)(ksrt * 64) * 3072;
    ka = *(const uint4*)(kr + koffA); kb = *(const uint4*)(kr + koffB);
    va = *(const uint4*)(vr + koffA); vb = *(const uint4*)(vr + koffB);
  }

  for (int kt2 = ksrt; kt2 <= kend; ++kt2){
    lds_barrier();   // prev-iter LDS reads done; in-flight global loads unaffected
    // ---- issue bias loads for CUR tile (consumed at mask step, after barrier)
    union B4 { uint4 v; uint32_t e[4]; } bb0, bb1, bb2, bb3;
    {
      const uint32_t* tp = bthread + ((size_t)(tribase + kt2) << 12);
      bb0.v = *(const uint4*)(tp + 0);
      bb1.v = *(const uint4*)(tp + 4);
      bb2.v = *(const uint4*)(tp + 8);
      bb3.v = *(const uint4*)(tp + 12);
    }
    // ---- LDS writes from prefetched regs (compiler waits vmcnt for ka..vb only)
    *(uint4*)(Ks + keyA * 72 + hdA) = ka;
    *(uint4*)(Ks + keyB * 72 + hdB) = kb;
    {
      union { uint4 u; f16 hh[8]; } ua, ub;
      ua.u = va; ub.u = vb;
      #pragma unroll
      for (int jj = 0; jj < 8; ++jj){
        Vt[(hdA + jj) * 72 + (sA << 3) + (keyA & 7)] = ua.hh[jj];
        Vt[(hdB + jj) * 72 + (sB << 3) + (keyB & 7)] = ub.hh[jj];
      }
    }
    // ---- issue NEXT tile's K/V (in flight across barrier + whole compute phase)
    if (kt2 < kend){
      const f16* kr = kbase + (size_t)((kt2 + 1) * 64) * 3072;
      const f16* vr = vbase + (size_t)((kt2 + 1) * 64) * 3072;
      ka = *(const uint4*)(kr + koffA); kb = *(const uint4*)(kr + koffB);
      va = *(const uint4*)(vr + koffA); vb = *(const uint4*)(vr + koffB);
    }
    lds_barrier();

    // ---- S = Q K^T
    f32x4 sf[4];
    #pragma unroll
    for (int nb = 0; nb < 4; ++nb){
      f32x4 s = {0.f, 0.f, 0.f, 0.f};
      f16x8 kf0 = *(const f16x8*)(Ks + (nb * 16 + lrow) * 72 + quad * 8);
      f16x8 kf1 = *(const f16x8*)(Ks + (nb * 16 + lrow) * 72 + 32 + quad * 8);
      s = __builtin_amdgcn_mfma_f32_16x16x32_f16(qf0, kf0, s, 0, 0, 0);
      s = __builtin_amdgcn_mfma_f32_16x16x32_f16(qf1, kf1, s, 0, 0, 0);
      sf[nb] = s;
    }

    // ---- bias + causal mask (C-layout: row = quad*4+r, col = lrow), log2-domain
    int kgb = kt2 * 64 + lrow;
    float sarr[4][4];
    bool diag = (kt2 == qt);
#define MASK_NB(nb, BB)                                                          \
    {                                                                            \
      int kg = kgb + nb * 16;                                                    \
      _Pragma("unroll")                                                          \
      for (int r = 0; r < 4; ++r){                                               \
        float v;                                                                 \
        if (diag && kg > qgb + r) v = -1e30f;                                    \
        else {                                                                   \
          uint32_t bp = BB.e[r];                                                 \
          union { ushort_t u; f16 h; } cv; cv.u = (ushort_t)bp;                  \
          v = sf[nb][r] * SCL + adjb * (float)cv.h + edge_lds[erep + (bp >> 16)];\
        }                                                                        \
        sarr[nb][r] = v;                                                         \
      }                                                                          \
    }
    MASK_NB(0, bb0)
    MASK_NB(1, bb1)
    MASK_NB(2, bb2)
    MASK_NB(3, bb3)
#undef MASK_NB

    // ---- online softmax, deferred-max (skip rescale unless max grew > 5 log2 units)
    float mx[4];
    bool need = false;
    #pragma unroll
    for (int r = 0; r < 4; ++r){
      float m_ = fmaxf(fmaxf(sarr[0][r], sarr[1][r]), fmaxf(sarr[2][r], sarr[3][r]));
      m_ = fmaxf(m_, __shfl_xor(m_, 1));
      m_ = fmaxf(m_, __shfl_xor(m_, 2));
      m_ = fmaxf(m_, __shfl_xor(m_, 4));
      m_ = fmaxf(m_, __shfl_xor(m_, 8));
      mx[r] = m_;
      need = need || (m_ > mrun[r] + 5.0f);
    }
    if (__any(need)){
      #pragma unroll
      for (int r = 0; r < 4; ++r){
        float mnew = fmaxf(mrun[r], mx[r]);
        float alpha = exp2f(mrun[r] - mnew);
        lrun[r] *= alpha;
        #pragma unroll
        for (int nbh = 0; nbh < 4; ++nbh) o[nbh][r] *= alpha;
        mrun[r] = mnew;
      }
    }
    float pv_[4][4];
    #pragma unroll
    for (int r = 0; r < 4; ++r){
      float rs = 0.f;
      #pragma unroll
      for (int nb = 0; nb < 4; ++nb){
        float p = exp2f(sarr[nb][r] - mrun[r]);
        pv_[nb][r] = p; rs += p;
      }
      rs += __shfl_xor(rs, 1); rs += __shfl_xor(rs, 2);
      rs += __shfl_xor(rs, 4); rs += __shfl_xor(rs, 8);
      lrun[r] += rs;
    }

    // ---- P: C-layout -> LDS (pitch 72) -> A-layout (wave-private)
    f16* Pw = &Ps[w][0];
    #pragma unroll
    for (int nb = 0; nb < 4; ++nb)
      #pragma unroll
      for (int r = 0; r < 4; ++r)
        Pw[(quad * 4 + r) * 72 + nb * 16 + lrow] = (f16)pv_[nb][r];
    __asm__ volatile("s_waitcnt lgkmcnt(0)" ::: "memory");

    // ---- O += P V  (Vt b128 fragments, swizzled)
    #pragma unroll
    for (int cc = 0; cc < 2; ++cc){
      f16x8 pf = *(const f16x8*)(Pw + lrow * 72 + cc * 32 + quad * 8);
      #pragma unroll
      for (int nbh = 0; nbh < 4; ++nbh){
        int hd = nbh * 16 + lrow;
        int sb = (hd >> 3) & 7;
        f16x8 vf = *(const f16x8*)(Vt + hd * 72 + (((cc * 4 + quad) ^ sb) << 3));
        o[nbh] = __builtin_amdgcn_mfma_f32_16x16x32_f16(pf, vf, o[nbh], 0, 0, 0);
      }
    }
  }

  if (whole){
    float inv[4];
    #pragma unroll
    for (int r = 0; r < 4; ++r) inv[r] = 1.0f / lrun[r];
    #pragma unroll
    for (int nbh = 0; nbh < 4; ++nbh)
      #pragma unroll
      for (int r = 0; r < 4; ++r){
        int qg = q0 + quad * 4 + r;
        int col = h * 64 + nbh * 16 + lrow;
        attn_out[((size_t)b * TT + qg) * 1024 + col] = (f16)(o[nbh][r] * inv[r]);
      }
  } else {
    int slot = bh * 72 + slot_base(qt) + ci;
    f16* Ob = Opart + (size_t)slot * 4096;
    #pragma unroll
    for (int nbh = 0; nbh < 4; ++nbh)
      #pragma unroll
      for (int r = 0; r < 4; ++r)
        Ob[(w * 16 + quad * 4 + r) * 64 + nbh * 16 + lrow] = (f16)o[nbh][r];
    if (lrow == 0){
      #pragma unroll
      for (int r = 0; r < 4; ++r){
        int qq = w * 16 + quad * 4 + r;
        MLpart[(size_t)slot * 128 + qq] = mrun[r];
        MLpart[(size_t)slot * 128 + 64 + qq] = lrun[r];
      }
    }
  }
}

// ---------------- combine 2..4 partial chunks for qt>=8 ----------------
__global__ __launch_bounds__(256) void combine_kernel(const f16* __restrict__ Opart,
                                                      const float* __restrict__ ML,
                                                      f16* __restrict__ attn_out){
  int qt = blockIdx.x + 8;          // 8..31
  int bh = blockIdx.y;              // 0..31
  int nch = (qt >> 3) + 1;          // 2..4
  int slot0 = bh * 72 + slot_base(qt);
  int t = threadIdx.x;
  int q = t >> 2;
  int hd0 = (t & 3) << 4;

  float m[4], l[4];
  float M = -1e30f;
  #pragma unroll
  for (int c = 0; c < 4; ++c){
    if (c < nch){
      m[c] = ML[(size_t)(slot0 + c) * 128 + q];
      l[c] = ML[(size_t)(slot0 + c) * 128 + 64 + q];
      M = fmaxf(M, m[c]);
    } else { m[c] = -1e30f; l[c] = 0.f; }
  }
  float acc[16];
  #pragma unroll
  for (int i = 0; i < 16; ++i) acc[i] = 0.f;
  float L = 0.f;
  #pragma unroll
  for (int c = 0; c < 4; ++c){
    if (c < nch){
      float wgt = exp2f(m[c] - M);
      L += l[c] * wgt;
      const f16* O = Opart + (size_t)(slot0 + c) * 4096 + q * 64 + hd0;
      f16x8 a0 = *(const f16x8*)O, a1 = *(const f16x8*)(O + 8);
      #pragma unroll
      for (int i = 0; i < 8; ++i){
        acc[i]     += (float)a0[i] * wgt;
        acc[i + 8] += (float)a1[i] * wgt;
      }
    }
  }
  float invL = 1.0f / L;
  f16 outv[16];
  #pragma unroll
  for (int i = 0; i < 16; ++i) outv[i] = (f16)(acc[i] * invL);
  int b = bh >> 4, h = bh & 15;
  f16* dst = attn_out + ((size_t)b * TT + qt * 64 + q) * 1024 + h * 64 + hd0;
  *(uint4*)dst = *(uint4*)&outv[0];
  *(uint4*)(dst + 8) = *(uint4*)&outv[8];
}

extern "C" void kernel_launch(void* const* d_in, const int* in_sizes, int n_in,
                              void* d_out, int out_size, void* d_ws, size_t ws_size,
                              hipStream_t stream){
  (void)in_sizes; (void)n_in; (void)out_size; (void)ws_size;
  const float* x_f32  = (const float*)d_in[0];
  const float* gadj   = (const float*)d_in[1];
  const int*   etype  = (const int*)d_in[2];
  const float* wqkv   = (const float*)d_in[3];
  const float* wproj  = (const float*)d_in[4];
  const float* adjb   = (const float*)d_in[5];
  const float* etab   = (const float*)d_in[6];

  // workspace layout (peak ~72.3 MB):
  //  [0,8)    x_f16, reused as attn_out
  //  [8,32)   qkv
  //  [32,38)  wqkvT (dead after qkv GEMM) -- aliased by Opart [32,50.9)
  //  [51,53)  wprojT
  //  [53,54.2) MLpart
  //  [55,72.3) pbias (triangle-compressed u32 tiles, fragment order)
  char* ws = (char*)d_ws;
  f16*     x_f16  = (f16*)(ws);
  f16*     qkv    = (f16*)(ws + (8u  << 20));
  f16*     wqkvT  = (f16*)(ws + (32u << 20));
  f16*     Opart  = (f16*)(ws + (32u << 20));
  f16*     wprojT = (f16*)(ws + (51u << 20));
  float*   MLpart = (float*)(ws + (53u << 20));
  uint32_t* pbias = (uint32_t*)(ws + (55u << 20));
  f16*     attn_o = x_f16;  // reuse

  cvt_f2h_kernel<<<4096, 256, 0, stream>>>((const float4*)x_f32, (uint2*)x_f16, 1048576);
  pack_bias_kernel<<<1056, 256, 0, stream>>>(gadj, etype, pbias);
  transpose_cvt_kernel<<<dim3(48, 16), 256, 0, stream>>>(wqkv, wqkvT, 1024, 3072);
  transpose_cvt_kernel<<<dim3(16, 16), 256, 0, stream>>>(wproj, wprojT, 1024, 1024);
  gemm_f16_kernel<<<dim3(24, 32), 256, 0, stream>>>(x_f16, wqkvT, qkv, 4096, 3072, 1024, 0);
  attn_kernel<<<2560, 256, 0, stream>>>(qkv, pbias, adjb, etab, attn_o, Opart, MLpart);
  combine_kernel<<<dim3(24, 32), 256, 0, stream>>>(Opart, MLpart, attn_o);
  gemm_f16_kernel<<<dim3(8, 32), 256, 0, stream>>>(attn_o, wprojT, d_out, 4096, 1024, 1024, 1);
}

// Round 4
// 282.858 us; speedup vs baseline: 1.2642x; 1.0454x over previous
//
#include <hip/hip_runtime.h>
#include <stdint.h>

#define TT 2048
#define HH 16
#define LOG2E 1.44269504089f

typedef _Float16 f16;
typedef __attribute__((ext_vector_type(8))) _Float16 f16x8;
typedef __attribute__((ext_vector_type(4))) float f32x4;
typedef unsigned short ushort_t;

// async global->LDS, 16B per lane (GEMM only)
__device__ __forceinline__ void gl_lds16(const void* g, void* l){
  __builtin_amdgcn_global_load_lds(
      (__attribute__((address_space(1))) void*)(void*)g,
      (__attribute__((address_space(3))) void*)l, 16, 0, 0);
}

// barrier WITHOUT vmcnt drain: LDS ops done, but global loads stay in flight
__device__ __forceinline__ void lds_barrier(){
  __asm__ volatile("s_waitcnt lgkmcnt(0)\n\ts_barrier" ::: "memory");
}

// ---- DPP-based 16-lane row reduction (VALU, no LDS pipe) ----
// groups = 16 consecutive lanes (quad*16 + lrow). quad_perm for xor1/xor2,
// row_ror:4/8 (rotation-reduce: converges for commutative ops over a row).
template<int CTRL>
__device__ __forceinline__ float dpp_mov(float x){
  int xi = __builtin_bit_cast(int, x);
  return __builtin_bit_cast(float,
      __builtin_amdgcn_update_dpp(xi, xi, CTRL, 0xF, 0xF, false));
}
__device__ __forceinline__ float row_red_max(float x){
  x = fmaxf(x, dpp_mov<0xB1>(x));   // quad_perm [1,0,3,2]  (xor 1)
  x = fmaxf(x, dpp_mov<0x4E>(x));   // quad_perm [2,3,0,1]  (xor 2)
  x = fmaxf(x, dpp_mov<0x124>(x));  // row_ror:4
  x = fmaxf(x, dpp_mov<0x128>(x));  // row_ror:8
  return x;
}
__device__ __forceinline__ float row_red_sum(float x){
  x += dpp_mov<0xB1>(x);
  x += dpp_mov<0x4E>(x);
  x += dpp_mov<0x124>(x);
  x += dpp_mov<0x128>(x);
  return x;
}

// ---------------- block schedule (chunk = 8 k-tiles), LPT order ----------------
struct SchedT { unsigned short v[80]; };
static constexpr SchedT make_sched(){
  SchedT s{};
  int idx = 0;
  for (int size = 8; size >= 1; --size){
    for (int qt = 31; qt >= 8; --qt){
      int full = qt >> 3;
      int tail = (qt & 7) + 1;
      if (size == 8)
        for (int ci = 0; ci < full; ++ci)
          s.v[idx++] = (unsigned short)(qt | (ci << 8));
      if (tail == size)
        s.v[idx++] = (unsigned short)(qt | (full << 8));
    }
    s.v[idx++] = (unsigned short)(size - 1);
  }
  return s;
}
__constant__ SchedT SCHED = make_sched();

// prefix of partial-slot count: slots for qt' in [8, qt)
__device__ __forceinline__ int slot_base(int qt){
  return (qt < 16) ? 2 * (qt - 8)
       : (qt < 24) ? 16 + 3 * (qt - 16)
                   : 40 + 4 * (qt - 24);
}

// ---------------- convert x: f32 -> f16 ----------------
__global__ __launch_bounds__(256) void cvt_f2h_kernel(const float4* __restrict__ in,
                                                      uint2* __restrict__ out, int n4){
  int i = blockIdx.x * 256 + threadIdx.x;
  if (i >= n4) return;
  float4 v = in[i];
  union { f16 h[4]; uint2 u; } o;
  o.h[0] = (f16)v.x; o.h[1] = (f16)v.y; o.h[2] = (f16)v.z; o.h[3] = (f16)v.w;
  out[i] = o.u;
}

// ---------------- pack bias: lower-triangle 64x64 tiles, FRAGMENT order ----------------
// out[tile][t][j]: t = attn thread id (w*64 + quad*16 + lrow), j = nb*4 + r.
// element (qrow = (t>>6)*16 + ((t>>4)&3)*4 + r, col = nb*16 + (t&15)) of the tile.
// value = f16(gadj) | etype<<16. Coalesced reads, scattered u32 writes (one-shot).
__global__ __launch_bounds__(256) void pack_bias_kernel(const float* __restrict__ gadj,
                                                        const int* __restrict__ etype,
                                                        uint32_t* __restrict__ out){
  int bid = blockIdx.x;
  int b = bid / 528, ti = bid - b * 528;
  int qt = (int)((sqrtf(8.f * (float)ti + 1.f) - 1.f) * 0.5f);
  while ((qt + 1) * (qt + 2) / 2 <= ti) ++qt;
  while (qt * (qt + 1) / 2 > ti) --qt;
  int kt = ti - qt * (qt + 1) / 2;

  int t = threadIdx.x;
  int row = t >> 2, c0 = (t & 3) << 4;     // this thread reads row, cols c0..c0+15
  size_t src = ((size_t)b * TT + qt * 64 + row) * TT + kt * 64 + c0;
  uint32_t* dst = out + (size_t)bid * 4096;
  // fragment coords of (row, col): w=row>>4, quad=(row&15)>>2, r=row&3, nb=col>>4=t&3, lrow=col&15
  int wq = (row >> 4) * 64 + ((row & 15) >> 2) * 16;   // + lrow gives t'
  int jbase = (t & 3) * 4 + (row & 3);                 // nb*4 + r
  #pragma unroll
  for (int v4 = 0; v4 < 4; ++v4){
    float4 g = *(const float4*)(gadj + src + v4 * 4);
    int4   e = *(const int4*)(etype + src + v4 * 4);
    union { f16 h; ushort_t u; } c;
    c.h = (f16)g.x; dst[(wq + v4 * 4 + 0) * 16 + jbase] = (uint32_t)c.u | ((uint32_t)e.x << 16);
    c.h = (f16)g.y; dst[(wq + v4 * 4 + 1) * 16 + jbase] = (uint32_t)c.u | ((uint32_t)e.y << 16);
    c.h = (f16)g.z; dst[(wq + v4 * 4 + 2) * 16 + jbase] = (uint32_t)c.u | ((uint32_t)e.z << 16);
    c.h = (f16)g.w; dst[(wq + v4 * 4 + 3) * 16 + jbase] = (uint32_t)c.u | ((uint32_t)e.w << 16);
  }
}

// ---------------- transpose+convert: f32 [R][C] -> f16 [C][R] ----------------
__global__ __launch_bounds__(256) void transpose_cvt_kernel(const float* __restrict__ in,
                                                            f16* __restrict__ out, int R, int C){
  __shared__ float tile[64][65];
  int c0 = blockIdx.x * 64, r0 = blockIdx.y * 64;
  int t = threadIdx.x;
  int row = t >> 2, cs = (t & 3) << 4;
  const float4* src = (const float4*)(in + (size_t)(r0 + row) * C + c0 + cs);
  float4 a = src[0], b = src[1], c = src[2], d = src[3];
  float* tr = &tile[row][cs];
  tr[0]=a.x; tr[1]=a.y; tr[2]=a.z;  tr[3]=a.w;
  tr[4]=b.x; tr[5]=b.y; tr[6]=b.z;  tr[7]=b.w;
  tr[8]=c.x; tr[9]=c.y; tr[10]=c.z; tr[11]=c.w;
  tr[12]=d.x;tr[13]=d.y;tr[14]=d.z; tr[15]=d.w;
  __syncthreads();
  f16 tmp[16];
  #pragma unroll
  for (int j = 0; j < 16; ++j) tmp[j] = (f16)tile[cs + j][row];
  f16* dst = out + (size_t)(c0 + row) * R + r0 + cs;
  *(uint4*)dst = *(uint4*)&tmp[0];
  *(uint4*)(dst + 8) = *(uint4*)&tmp[8];
}

// ---------------- GEMM: C[M][N] = A[M][K] @ Bt[N][K]^T ----------------
__global__ __launch_bounds__(256) void gemm_f16_kernel(const f16* __restrict__ A,
                                                       const f16* __restrict__ Bt,
                                                       void* __restrict__ Cout,
                                                       int M, int N, int K, int out_f32){
  __shared__ __align__(16) f16 As[128 * 32];
  __shared__ __align__(16) f16 Bs[128 * 32];
  int t = threadIdx.x;
  int w = t >> 6, lane = t & 63;
  int wm = (w >> 1) * 64, wn = (w & 1) * 64;
  int lrow = lane & 15, quad = lane >> 4;
  int bm = blockIdx.y, bn = blockIdx.x;

  f32x4 acc[4][4];
  for (int i = 0; i < 4; ++i)
    for (int j = 0; j < 4; ++j)
      for (int r = 0; r < 4; ++r) acc[i][j][r] = 0.f;

  const int nk = K >> 5;
  for (int kt = 0; kt < nk; ++kt){
    int k0 = kt << 5;
    __syncthreads();
    #pragma unroll
    for (int i = 0; i < 2; ++i){
      int c = (w << 7) + (i << 6) + lane;
      gl_lds16(A  + (size_t)((bm << 7) + (c >> 2)) * K + k0 + ((c & 3) << 3),
               As + ((w << 7) + (i << 6)) * 8);
      gl_lds16(Bt + (size_t)((bn << 7) + (c >> 2)) * K + k0 + ((c & 3) << 3),
               Bs + ((w << 7) + (i << 6)) * 8);
    }
    __syncthreads();
    f16x8 af[4], bfr[4];
    #pragma unroll
    for (int mi = 0; mi < 4; ++mi)
      af[mi] = *(const f16x8*)(As + (wm + mi * 16 + lrow) * 32 + quad * 8);
    #pragma unroll
    for (int ni = 0; ni < 4; ++ni)
      bfr[ni] = *(const f16x8*)(Bs + (wn + ni * 16 + lrow) * 32 + quad * 8);
    #pragma unroll
    for (int mi = 0; mi < 4; ++mi)
      #pragma unroll
      for (int ni = 0; ni < 4; ++ni)
        acc[mi][ni] = __builtin_amdgcn_mfma_f32_16x16x32_f16(af[mi], bfr[ni], acc[mi][ni], 0, 0, 0);
  }

  #pragma unroll
  for (int mi = 0; mi < 4; ++mi)
    #pragma unroll
    for (int ni = 0; ni < 4; ++ni)
      #pragma unroll
      for (int r = 0; r < 4; ++r){
        int row = (bm << 7) + wm + mi * 16 + quad * 4 + r;
        int col = (bn << 7) + wn + ni * 16 + lrow;
        float val = acc[mi][ni][r];
        if (out_f32) ((float*)Cout)[(size_t)row * N + col] = val;
        else         ((f16*)Cout)[(size_t)row * N + col] = (f16)val;
      }
}

// ---------------- fused causal graph attention, split-K chunks of 8 tiles ----------------
// LDS-pipe diet: DPP softmax reduce (no ds_bpermute), 32-replica edge table
// (conflict-free lookups), paired-key V staging (8 b32 vs 16 b16 writes).
__global__ __launch_bounds__(256, 4) void attn_kernel(const f16* __restrict__ qkv,
                                                      const uint32_t* __restrict__ pbias,
                                                      const float* __restrict__ adj_bias,
                                                      const float* __restrict__ edge_table,
                                                      f16* __restrict__ attn_out,
                                                      f16* __restrict__ Opart,
                                                      float* __restrict__ MLpart){
  __shared__ __align__(16) f16 Ks[64 * 72];
  __shared__ __align__(16) f16 Vt[64 * 72];   // transposed [hd][key], xor-swizzled 16B blocks
  __shared__ __align__(16) f16 Ps[4][16 * 72];
  __shared__ float edge_lds[32 * 17];         // 32 replicas, stride 17 (bases cover all banks)

  int bx = blockIdx.x;
  int bh = bx & 31;
  int h = bh & 15, b = bh >> 4;
  int ej = SCHED.v[bx >> 5];
  int qt = ej & 31, ci = ej >> 8;
  int ksrt = ci << 3;
  int kend = min(qt, ksrt + 7);
  bool whole = (qt < 8);

  int t = threadIdx.x;
  int w = t >> 6, lane = t & 63;
  int lrow = lane & 15, quad = lane >> 4;

  for (int i = t; i < 544; i += 256)
    edge_lds[i] = edge_table[(i % 17) * HH + h] * LOG2E;
  float adjb = adj_bias[h] * LOG2E;
  int erep = (lane & 31) * 17;

  int q0 = qt * 64 + w * 16;
  const size_t qrow = ((size_t)b * TT + q0 + lrow) * 3072 + h * 64;
  f16x8 qf0 = *(const f16x8*)(qkv + qrow + quad * 8);
  f16x8 qf1 = *(const f16x8*)(qkv + qrow + 32 + quad * 8);

  f32x4 o[4];
  for (int i = 0; i < 4; ++i)
    for (int r = 0; r < 4; ++r) o[i][r] = 0.f;
  float mrun[4] = {-1e30f, -1e30f, -1e30f, -1e30f};
  float lrun[4] = {0.f, 0.f, 0.f, 0.f};

  // staging geometry: thread handles keys (keyA, keyA+1) x hd segment hdA..hdA+7
  const int keyA = (t >> 3) << 1;        // even key
  const int hdA  = (t & 7) << 3;
  const int sA   = ((keyA >> 3) ^ (hdA >> 3)) & 7;
  const f16* kbase = qkv + (size_t)b * TT * 3072 + 1024 + h * 64;
  const f16* vbase = qkv + (size_t)b * TT * 3072 + 2048 + h * 64;
  const size_t koffA = (size_t)keyA * 3072 + hdA;
  const size_t koffB = koffA + 3072;

  const float SCL = 0.125f * LOG2E;   // score scale, log2-domain

  // bias tile addressing (triangle-compressed, fragment-order layout)
  const int tribase = b * 528 + ((qt * (qt + 1)) >> 1);
  const uint32_t* bthread = pbias + ((size_t)t << 4);
  const int qgb = q0 + quad * 4;

  // ---- prefetch first tile's K/V into named regs
  uint4 ka, kb, va, vb;
  {
    const f16* kr = kbase + (size_t)(ksrt * 64) * 3072;
    const f16* vr = vbase + (size_t)(ksrt * 64) * 3072;
    ka = *(const uint4*)(kr + koffA); kb = *(const uint4*)(kr + koffB);
    va = *(const uint4*)(vr + koffA); vb = *(const uint4*)(vr + koffB);
  }

  for (int kt2 = ksrt; kt2 <= kend; ++kt2){
    lds_barrier();   // prev-iter LDS reads done; in-flight global loads unaffected
    // ---- issue bias loads for CUR tile (consumed at mask step, after barrier)
    union B4 { uint4 v; uint32_t e[4]; } bb0, bb1, bb2, bb3;
    {
      const uint32_t* tp = bthread + ((size_t)(tribase + kt2) << 12);
      bb0.v = *(const uint4*)(tp + 0);
      bb1.v = *(const uint4*)(tp + 4);
      bb2.v = *(const uint4*)(tp + 8);
      bb3.v = *(const uint4*)(tp + 12);
    }
    // ---- LDS writes from prefetched regs
    *(uint4*)(Ks + keyA * 72 + hdA) = ka;
    *(uint4*)(Ks + (keyA + 1) * 72 + hdA) = kb;
    {
      union { uint4 u; f16 hh[8]; } ua, ub;
      ua.u = va; ub.u = vb;
      #pragma unroll
      for (int jj = 0; jj < 8; ++jj){
        union { f16 h[2]; uint32_t wv; } pr;
        pr.h[0] = ua.hh[jj]; pr.h[1] = ub.hh[jj];
        *(uint32_t*)(Vt + (hdA + jj) * 72 + (sA << 3) + (keyA & 7)) = pr.wv;
      }
    }
    // ---- issue NEXT tile's K/V (in flight across barrier + whole compute phase)
    if (kt2 < kend){
      const f16* kr = kbase + (size_t)((kt2 + 1) * 64) * 3072;
      const f16* vr = vbase + (size_t)((kt2 + 1) * 64) * 3072;
      ka = *(const uint4*)(kr + koffA); kb = *(const uint4*)(kr + koffB);
      va = *(const uint4*)(vr + koffA); vb = *(const uint4*)(vr + koffB);
    }
    lds_barrier();

    // ---- S = Q K^T
    f32x4 sf[4];
    #pragma unroll
    for (int nb = 0; nb < 4; ++nb){
      f32x4 s = {0.f, 0.f, 0.f, 0.f};
      f16x8 kf0 = *(const f16x8*)(Ks + (nb * 16 + lrow) * 72 + quad * 8);
      f16x8 kf1 = *(const f16x8*)(Ks + (nb * 16 + lrow) * 72 + 32 + quad * 8);
      s = __builtin_amdgcn_mfma_f32_16x16x32_f16(qf0, kf0, s, 0, 0, 0);
      s = __builtin_amdgcn_mfma_f32_16x16x32_f16(qf1, kf1, s, 0, 0, 0);
      sf[nb] = s;
    }

    // ---- bias + causal mask (C-layout: row = quad*4+r, col = lrow), log2-domain
    int kgb = kt2 * 64 + lrow;
    float sarr[4][4];
    bool diag = (kt2 == qt);
#define MASK_NB(nb, BB)                                                          \
    {                                                                            \
      int kg = kgb + nb * 16;                                                    \
      _Pragma("unroll")                                                          \
      for (int r = 0; r < 4; ++r){                                               \
        float v;                                                                 \
        if (diag && kg > qgb + r) v = -1e30f;                                    \
        else {                                                                   \
          uint32_t bp = BB.e[r];                                                 \
          union { ushort_t u; f16 h; } cv; cv.u = (ushort_t)bp;                  \
          v = sf[nb][r] * SCL + adjb * (float)cv.h + edge_lds[erep + (bp >> 16)];\
        }                                                                        \
        sarr[nb][r] = v;                                                         \
      }                                                                          \
    }
    MASK_NB(0, bb0)
    MASK_NB(1, bb1)
    MASK_NB(2, bb2)
    MASK_NB(3, bb3)
#undef MASK_NB

    // ---- online softmax (DPP row-reduce), deferred-max (skip rescale unless >5 log2 units)
    float mx[4];
    bool need = false;
    #pragma unroll
    for (int r = 0; r < 4; ++r){
      float m_ = fmaxf(fmaxf(sarr[0][r], sarr[1][r]), fmaxf(sarr[2][r], sarr[3][r]));
      m_ = row_red_max(m_);
      mx[r] = m_;
      need = need || (m_ > mrun[r] + 5.0f);
    }
    if (__any(need)){
      #pragma unroll
      for (int r = 0; r < 4; ++r){
        float mnew = fmaxf(mrun[r], mx[r]);
        float alpha = exp2f(mrun[r] - mnew);
        lrun[r] *= alpha;
        #pragma unroll
        for (int nbh = 0; nbh < 4; ++nbh) o[nbh][r] *= alpha;
        mrun[r] = mnew;
      }
    }
    float pv_[4][4];
    #pragma unroll
    for (int r = 0; r < 4; ++r){
      float rs = 0.f;
      #pragma unroll
      for (int nb = 0; nb < 4; ++nb){
        float p = exp2f(sarr[nb][r] - mrun[r]);
        pv_[nb][r] = p; rs += p;
      }
      rs = row_red_sum(rs);
      lrun[r] += rs;
    }

    // ---- P: C-layout -> LDS (pitch 72) -> A-layout (wave-private)
    f16* Pw = &Ps[w][0];
    #pragma unroll
    for (int nb = 0; nb < 4; ++nb)
      #pragma unroll
      for (int r = 0; r < 4; ++r)
        Pw[(quad * 4 + r) * 72 + nb * 16 + lrow] = (f16)pv_[nb][r];
    __asm__ volatile("s_waitcnt lgkmcnt(0)" ::: "memory");

    // ---- O += P V  (Vt b128 fragments, swizzled)
    #pragma unroll
    for (int cc = 0; cc < 2; ++cc){
      f16x8 pf = *(const f16x8*)(Pw + lrow * 72 + cc * 32 + quad * 8);
      #pragma unroll
      for (int nbh = 0; nbh < 4; ++nbh){
        int hd = nbh * 16 + lrow;
        int sb = (hd >> 3) & 7;
        f16x8 vf = *(const f16x8*)(Vt + hd * 72 + (((cc * 4 + quad) ^ sb) << 3));
        o[nbh] = __builtin_amdgcn_mfma_f32_16x16x32_f16(pf, vf, o[nbh], 0, 0, 0);
      }
    }
  }

  if (whole){
    float inv[4];
    #pragma unroll
    for (int r = 0; r < 4; ++r) inv[r] = 1.0f / lrun[r];
    #pragma unroll
    for (int nbh = 0; nbh < 4; ++nbh)
      #pragma unroll
      for (int r = 0; r < 4; ++r){
        int qg = q0 + quad * 4 + r;
        int col = h * 64 + nbh * 16 + lrow;
        attn_out[((size_t)b * TT + qg) * 1024 + col] = (f16)(o[nbh][r] * inv[r]);
      }
  } else {
    int slot = bh * 72 + slot_base(qt) + ci;
    f16* Ob = Opart + (size_t)slot * 4096;
    #pragma unroll
    for (int nbh = 0; nbh < 4; ++nbh)
      #pragma unroll
      for (int r = 0; r < 4; ++r)
        Ob[(w * 16 + quad * 4 + r) * 64 + nbh * 16 + lrow] = (f16)o[nbh][r];
    if (lrow == 0){
      #pragma unroll
      for (int r = 0; r < 4; ++r){
        int qq = w * 16 + quad * 4 + r;
        MLpart[(size_t)slot * 128 + qq] = mrun[r];
        MLpart[(size_t)slot * 128 + 64 + qq] = lrun[r];
      }
    }
  }
}

// ---------------- combine 2..4 partial chunks for qt>=8 ----------------
__global__ __launch_bounds__(256) void combine_kernel(const f16* __restrict__ Opart,
                                                      const float* __restrict__ ML,
                                                      f16* __restrict__ attn_out){
  int qt = blockIdx.x + 8;          // 8..31
  int bh = blockIdx.y;              // 0..31
  int nch = (qt >> 3) + 1;          // 2..4
  int slot0 = bh * 72 + slot_base(qt);
  int t = threadIdx.x;
  int q = t >> 2;
  int hd0 = (t & 3) << 4;

  float m[4], l[4];
  float M = -1e30f;
  #pragma unroll
  for (int c = 0; c < 4; ++c){
    if (c < nch){
      m[c] = ML[(size_t)(slot0 + c) * 128 + q];
      l[c] = ML[(size_t)(slot0 + c) * 128 + 64 + q];
      M = fmaxf(M, m[c]);
    } else { m[c] = -1e30f; l[c] = 0.f; }
  }
  float acc[16];
  #pragma unroll
  for (int i = 0; i < 16; ++i) acc[i] = 0.f;
  float L = 0.f;
  #pragma unroll
  for (int c = 0; c < 4; ++c){
    if (c < nch){
      float wgt = exp2f(m[c] - M);
      L += l[c] * wgt;
      const f16* O = Opart + (size_t)(slot0 + c) * 4096 + q * 64 + hd0;
      f16x8 a0 = *(const f16x8*)O, a1 = *(const f16x8*)(O + 8);
      #pragma unroll
      for (int i = 0; i < 8; ++i){
        acc[i]     += (float)a0[i] * wgt;
        acc[i + 8] += (float)a1[i] * wgt;
      }
    }
  }
  float invL = 1.0f / L;
  f16 outv[16];
  #pragma unroll
  for (int i = 0; i < 16; ++i) outv[i] = (f16)(acc[i] * invL);
  int b = bh >> 4, h = bh & 15;
  f16* dst = attn_out + ((size_t)b * TT + qt * 64 + q) * 1024 + h * 64 + hd0;
  *(uint4*)dst = *(uint4*)&outv[0];
  *(uint4*)(dst + 8) = *(uint4*)&outv[8];
}

extern "C" void kernel_launch(void* const* d_in, const int* in_sizes, int n_in,
                              void* d_out, int out_size, void* d_ws, size_t ws_size,
                              hipStream_t stream){
  (void)in_sizes; (void)n_in; (void)out_size; (void)ws_size;
  const float* x_f32  = (const float*)d_in[0];
  const float* gadj   = (const float*)d_in[1];
  const int*   etype  = (const int*)d_in[2];
  const float* wqkv   = (const float*)d_in[3];
  const float* wproj  = (const float*)d_in[4];
  const float* adjb   = (const float*)d_in[5];
  const float* etab   = (const float*)d_in[6];

  // workspace layout (peak ~72.3 MB):
  //  [0,8)    x_f16, reused as attn_out
  //  [8,32)   qkv
  //  [32,38)  wqkvT (dead after qkv GEMM) -- aliased by Opart [32,50.9)
  //  [51,53)  wprojT
  //  [53,54.2) MLpart
  //  [55,72.3) pbias (triangle-compressed u32 tiles, fragment order)
  char* ws = (char*)d_ws;
  f16*     x_f16  = (f16*)(ws);
  f16*     qkv    = (f16*)(ws + (8u  << 20));
  f16*     wqkvT  = (f16*)(ws + (32u << 20));
  f16*     Opart  = (f16*)(ws + (32u << 20));
  f16*     wprojT = (f16*)(ws + (51u << 20));
  float*   MLpart = (float*)(ws + (53u << 20));
  uint32_t* pbias = (uint32_t*)(ws + (55u << 20));
  f16*     attn_o = x_f16;  // reuse

  cvt_f2h_kernel<<<4096, 256, 0, stream>>>((const float4*)x_f32, (uint2*)x_f16, 1048576);
  pack_bias_kernel<<<1056, 256, 0, stream>>>(gadj, etype, pbias);
  transpose_cvt_kernel<<<dim3(48, 16), 256, 0, stream>>>(wqkv, wqkvT, 1024, 3072);
  transpose_cvt_kernel<<<dim3(16, 16), 256, 0, stream>>>(wproj, wprojT, 1024, 1024);
  gemm_f16_kernel<<<dim3(24, 32), 256, 0, stream>>>(x_f16, wqkvT, qkv, 4096, 3072, 1024, 0);
  attn_kernel<<<2560, 256, 0, stream>>>(qkv, pbias, adjb, etab, attn_o, Opart, MLpart);
  combine_kernel<<<dim3(24, 32), 256, 0, stream>>>(Opart, MLpart, attn_o);
  gemm_f16_kernel<<<dim3(8, 32), 256, 0, stream>>>(attn_o, wprojT, d_out, 4096, 1024, 1024, 1);
}